// Round 2
// baseline (1614.718 us; speedup 1.0000x reference)
//
#include <hip/hip_runtime.h>

// ---------------- constants ----------------
constexpr int S = 197;
constexpr int B = 64;
constexpr int E = 768;
constexpr int H = 12;
constexpr int D = 64;
constexpr int M = S * B;                  // 12608 rows, qkv GEMM order m = s*B+b
constexpr size_t SBE = (size_t)M * E;     // floats in one [*,768] buffer (9,682,944)
constexpr size_t AVGN = (size_t)B * S * S;

// ---------------- block reductions (ln) ----------------
__device__ __forceinline__ float bsum(float v, float* sm, int tid) {
#pragma unroll
  for (int off = 32; off > 0; off >>= 1) v += __shfl_down(v, off, 64);
  if ((tid & 63) == 0) sm[tid >> 6] = v;
  __syncthreads();
  float r = sm[0] + sm[1] + sm[2] + sm[3];
  __syncthreads();
  return r;
}

// ---------------- R[s,t] = rel[196+s] . rel[196+t] ----------------
__global__ __launch_bounds__(256) void mha_relR(const float* __restrict__ rel,
                                                float* __restrict__ Rb) {
  int idx = blockIdx.x * 256 + threadIdx.x;
  if (idx >= S * S) return;
  int s = idx / S, t = idx - s * S;
  const float* a = rel + (size_t)(S - 1 + s) * D;
  const float* b = rel + (size_t)(S - 1 + t) * D;
  float acc = 0.f;
#pragma unroll 8
  for (int d = 0; d < D; ++d) acc = fmaf(a[d], b[d], acc);
  Rb[idx] = acc;
}

// ---------------- QKV grouped GEMM, pass A: y[m][p] natural (coalesced) --------
// y is chunk-local: rows [mbase, mbase+rows).
__global__ __launch_bounds__(256) void mha_qkv_gemm(const float* __restrict__ x,
                                                    const float* __restrict__ w,
                                                    const float* __restrict__ bias,
                                                    float* __restrict__ y,
                                                    int mbase, int rows) {
  __shared__ float Xt[96][68];   // [k][m], float4-aligned a-loads
  __shared__ float Ws[96][98];   // [k][n], float2-aligned b-loads
  const int m0 = mbase + blockIdx.x * 64;
  const int n0 = blockIdx.y * 96;
  const int g = n0 / 288;
  const int tid = threadIdx.x;
  for (int idx = tid; idx < 64 * 96; idx += 256) {
    int mm = idx / 96, k = idx - mm * 96;
    Xt[k][mm] = x[(size_t)(m0 + mm) * E + g * 96 + k];
  }
  for (int idx = tid; idx < 96 * 96; idx += 256) {
    int n = idx / 96, k = idx - n * 96;
    Ws[k][n] = w[(size_t)(n0 + n) * 96 + k];
  }
  __syncthreads();
  const int tx = tid & 15, ty = tid >> 4;
  float acc[4][6] = {};
  for (int k = 0; k < 96; ++k) {
    float4 a = *reinterpret_cast<const float4*>(&Xt[k][ty * 4]);
    float2 w0 = *reinterpret_cast<const float2*>(&Ws[k][tx * 6]);
    float2 w1 = *reinterpret_cast<const float2*>(&Ws[k][tx * 6 + 2]);
    float2 w2 = *reinterpret_cast<const float2*>(&Ws[k][tx * 6 + 4]);
    float av[4] = {a.x, a.y, a.z, a.w};
    float bv[6] = {w0.x, w0.y, w1.x, w1.y, w2.x, w2.y};
#pragma unroll
    for (int r = 0; r < 4; ++r)
#pragma unroll
      for (int c = 0; c < 6; ++c) acc[r][c] = fmaf(av[r], bv[c], acc[r][c]);
  }
  const int mloc = m0 - mbase + ty * 4;
#pragma unroll
  for (int r = 0; r < 4; ++r) {
#pragma unroll
    for (int c = 0; c < 6; ++c) {
      int p = n0 + tx * 6 + c;
      y[(size_t)(mloc + r) * 2304 + p] = acc[r][c] + bias[p];
    }
  }
}

// ---------------- QKV pass B: shuffle + head scatter + rel fold ----------------
// One wave covers a full 64-float head-row -> full-line writes, no amplification.
// blockIdx.y = which*12+h. lane: g=lane>>3, j=lane&7 -> reads p = g*288+base+j,
// which is the value of shuffled d = 8j+g; writes at d (perm within wave, same lines).
__global__ __launch_bounds__(256) void mha_qkv_shuffle(const float* __restrict__ y,
                                                       const float* __restrict__ rel,
                                                       float* __restrict__ qhat,
                                                       float* __restrict__ khat,
                                                       float* __restrict__ vbuf,
                                                       int mbase, int rows) {
  const int wh = blockIdx.y;
  const int which = wh / H, h = wh - which * H;
  const int basep = which * 96 + h * 8;
  const int tid = threadIdx.x;
  const int lane = tid & 63;
  const int g = lane >> 3, j = lane & 7;
  const int d = j * 8 + g;
  const int rbase = blockIdx.x * 32;
  float* dst = (which == 0) ? qhat : (which == 1) ? khat : vbuf;
#pragma unroll
  for (int r8 = 0; r8 < 8; ++r8) {
    int rowl = rbase + r8 * 4 + (tid >> 6);
    if (rowl >= rows) continue;
    int m = mbase + rowl;
    int s = m >> 6, b = m & 63;
    float val = y[(size_t)rowl * 2304 + g * 288 + basep + j];
    size_t o = (((size_t)b * H + h) * S + s) * D + d;
    if (which == 0)
      dst[o] = 0.125f * val + rel[(size_t)(S - 1 + s) * D + d];
    else if (which == 1)
      dst[o] = val + rel[(size_t)(S - 1 + s) * D + d];
    else
      dst[o] = val;
  }
}

// ---------------- fused attention: QK^T - R -> softmax -> avg atomic -> PV -----
// block: (bh, s-tile of 32). LDS: Ls[32][258], QsT[64][34], KV[64][68].
__global__ __launch_bounds__(256) void mha_fattn(const float* __restrict__ qhat,
                                                 const float* __restrict__ khat,
                                                 const float* __restrict__ vbuf,
                                                 const float* __restrict__ Rb,
                                                 float* __restrict__ context,
                                                 float* __restrict__ avg) {
  __shared__ float Ls[32 * 258];
  __shared__ float QsT[64 * 34];
  __shared__ float KV[64 * 68];
  const int bh = blockIdx.x;
  const int b_ = bh / H, h_ = bh - b_ * H;
  const int s0 = blockIdx.y * 32;
  const int tid = threadIdx.x;
  const int tx = tid & 15, ty = tid >> 4;

  // stage Q transposed [d][s], zero-pad s
  for (int idx = tid; idx < 64 * 32; idx += 256) {
    int dd = idx & 63, ss = idx >> 6;
    int sg = s0 + ss;
    QsT[dd * 34 + ss] = (sg < S) ? qhat[((size_t)bh * S + sg) * D + dd] : 0.f;
  }

  // ---- QK^T phase ----
  for (int tc = 0; tc < 4; ++tc) {
    const int t0 = tc * 64;
    __syncthreads();
    for (int idx = tid; idx < 64 * 64; idx += 256) {
      int dd = idx & 63, tt = idx >> 6;
      int tg = t0 + tt;
      KV[dd * 68 + tt] = (tg < S) ? khat[((size_t)bh * S + tg) * D + dd] : 0.f;
    }
    __syncthreads();
    float acc[2][4] = {};
    for (int dd = 0; dd < 64; ++dd) {
      float2 a = *reinterpret_cast<const float2*>(&QsT[dd * 34 + ty * 2]);
      float4 bb = *reinterpret_cast<const float4*>(&KV[dd * 68 + tx * 4]);
      float av[2] = {a.x, a.y};
      float bv[4] = {bb.x, bb.y, bb.z, bb.w};
#pragma unroll
      for (int r = 0; r < 2; ++r)
#pragma unroll
        for (int c = 0; c < 4; ++c) acc[r][c] = fmaf(av[r], bv[c], acc[r][c]);
    }
#pragma unroll
    for (int r = 0; r < 2; ++r) {
      int sl = ty * 2 + r, sg = s0 + sl;
#pragma unroll
      for (int c = 0; c < 4; ++c) {
        int tl = tx * 4 + c, tg = t0 + tl;
        float rv = (sg < S && tg < S) ? Rb[sg * S + tg] : 0.f;
        Ls[sl * 258 + t0 + tl] = acc[r][c] - rv;
      }
    }
  }
  __syncthreads();

  // ---- softmax + avg ----
  {
    const int row = tid >> 3, l8 = tid & 7;
    const int sg = s0 + row;
    float mx = -3.0e38f;
#pragma unroll
    for (int k = 0; k < 25; ++k) {
      int t = l8 + 8 * k;
      if (t < S) mx = fmaxf(mx, Ls[row * 258 + t]);
    }
#pragma unroll
    for (int off = 1; off < 8; off <<= 1) mx = fmaxf(mx, __shfl_xor(mx, off, 64));
    float sum = 0.f;
#pragma unroll
    for (int k = 0; k < 25; ++k) {
      int t = l8 + 8 * k;
      if (t < S) sum += __expf(Ls[row * 258 + t] - mx);
    }
#pragma unroll
    for (int off = 1; off < 8; off <<= 1) sum += __shfl_xor(sum, off, 64);
    float inv = 1.f / sum;
#pragma unroll
    for (int k = 0; k < 32; ++k) {
      int t = l8 + 8 * k;
      if (t < S) {
        float p = __expf(Ls[row * 258 + t] - mx) * inv;
        Ls[row * 258 + t] = p;
        if (sg < S)
          atomicAdd(&avg[((size_t)b_ * S + sg) * S + t], p * (1.f / H));
      } else if (t < 256) {
        Ls[row * 258 + t] = 0.f;
      }
    }
  }

  // ---- PV phase ----
  float acc2[2][4] = {};
  for (int tc = 0; tc < 4; ++tc) {
    const int t0 = tc * 64;
    __syncthreads();
    for (int idx = tid; idx < 64 * 64; idx += 256) {
      int dd = idx & 63, tt = idx >> 6;
      int tg = t0 + tt;
      KV[tt * 68 + dd] = (tg < S) ? vbuf[((size_t)bh * S + tg) * D + dd] : 0.f;
    }
    __syncthreads();
    for (int k = 0; k < 64; ++k) {
      float a0 = Ls[(ty * 2 + 0) * 258 + t0 + k];
      float a1 = Ls[(ty * 2 + 1) * 258 + t0 + k];
      float4 bb = *reinterpret_cast<const float4*>(&KV[k * 68 + tx * 4]);
      float bv[4] = {bb.x, bb.y, bb.z, bb.w};
#pragma unroll
      for (int c = 0; c < 4; ++c) {
        acc2[0][c] = fmaf(a0, bv[c], acc2[0][c]);
        acc2[1][c] = fmaf(a1, bv[c], acc2[1][c]);
      }
    }
  }
#pragma unroll
  for (int r = 0; r < 2; ++r) {
    int sg = s0 + ty * 2 + r;
    if (sg >= S) continue;
#pragma unroll
    for (int c = 0; c < 4; ++c) {
      int dd = tx * 4 + c;
      context[((size_t)b_ * S + sg) * E + h_ * D + dd] = acc2[r][c];
    }
  }
}

// ---------------- LayerNorm over E -------------------------------------------
__global__ __launch_bounds__(256) void mha_ln(const float* __restrict__ x,
                                              const float* __restrict__ g,
                                              const float* __restrict__ bb,
                                              float* __restrict__ y) {
  __shared__ float sm[4];
  const size_t r = blockIdx.x;
  const float* xr = x + r * E;
  const int tid = threadIdx.x;
  float s1 = 0.f, s2 = 0.f;
  for (int i = tid; i < E; i += 256) {
    float v = xr[i];
    s1 += v;
    s2 += v * v;
  }
  s1 = bsum(s1, sm, tid);
  s2 = bsum(s2, sm, tid);
  float mu = s1 * (1.f / E);
  float var = s2 * (1.f / E) - mu * mu;
  float inv = rsqrtf(var + 1e-5f);
  float* yr = y + r * E;
  for (int i = tid; i < E; i += 256) yr[i] = (xr[i] - mu) * inv * g[i] + bb[i];
}

// ---------------- fc1 (768->96) + tanh-gelu ------------------------------------
__global__ __launch_bounds__(256) void mha_fc1(const float* __restrict__ ln,
                                               const float* __restrict__ w,
                                               const float* __restrict__ bias,
                                               float* __restrict__ h1) {
  __shared__ float Ls2[64][33];
  __shared__ float Ws[32][97];
  const int m0 = blockIdx.x * 64;
  const int tid = threadIdx.x;
  const int tx = tid & 15, ty = tid >> 4;
  float acc[4][6] = {};
  for (int k0 = 0; k0 < E; k0 += 32) {
    for (int idx = tid; idx < 64 * 32; idx += 256) {
      int m = idx >> 5, k = idx & 31;
      Ls2[m][k] = ln[(size_t)(m0 + m) * E + k0 + k];
    }
    for (int idx = tid; idx < 32 * 96; idx += 256) {
      int k = idx / 96, n = idx - k * 96;
      Ws[k][n] = w[(size_t)(k0 + k) * 96 + n];
    }
    __syncthreads();
    for (int k = 0; k < 32; ++k) {
      float a[4], bb[6];
#pragma unroll
      for (int r = 0; r < 4; ++r) a[r] = Ls2[ty * 4 + r][k];
#pragma unroll
      for (int c = 0; c < 6; ++c) bb[c] = Ws[k][tx * 6 + c];
#pragma unroll
      for (int r = 0; r < 4; ++r)
#pragma unroll
        for (int c = 0; c < 6; ++c) acc[r][c] = fmaf(a[r], bb[c], acc[r][c]);
    }
    __syncthreads();
  }
#pragma unroll
  for (int r = 0; r < 4; ++r) {
    int m = m0 + ty * 4 + r;
#pragma unroll
    for (int c = 0; c < 6; ++c) {
      int n = tx * 6 + c;
      float u = acc[r][c] + bias[n];
      float gl = 0.5f * u * (1.f + tanhf(0.7978845608028654f * (u + 0.044715f * u * u * u)));
      h1[(size_t)m * 96 + n] = gl;
    }
  }
}

// ---------------- fc2 (96->768) + sigmoid, scale context -----------------------
__global__ __launch_bounds__(256) void mha_fc2(const float* __restrict__ h1,
                                               const float* __restrict__ w,
                                               const float* __restrict__ bias,
                                               const float* __restrict__ context,
                                               float* __restrict__ attn2) {
  __shared__ float Hs[64][97];
  __shared__ float Ws[96][65];
  const int m0 = blockIdx.x * 64;
  const int n0 = blockIdx.y * 64;
  const int tid = threadIdx.x;
  for (int idx = tid; idx < 64 * 96; idx += 256) {
    int m = idx / 96, k = idx - m * 96;
    Hs[m][k] = h1[(size_t)(m0 + m) * 96 + k];
  }
  for (int idx = tid; idx < 96 * 64; idx += 256) {
    int k = idx >> 6, n = idx & 63;
    Ws[k][n] = w[(size_t)k * E + n0 + n];
  }
  __syncthreads();
  const int tx = tid & 15, ty = tid >> 4;
  float acc[4][4] = {};
  for (int k = 0; k < 96; ++k) {
    float a[4], bb[4];
#pragma unroll
    for (int r = 0; r < 4; ++r) a[r] = Hs[ty * 4 + r][k];
#pragma unroll
    for (int c = 0; c < 4; ++c) bb[c] = Ws[k][tx * 4 + c];
#pragma unroll
    for (int r = 0; r < 4; ++r)
#pragma unroll
      for (int c = 0; c < 4; ++c) acc[r][c] = fmaf(a[r], bb[c], acc[r][c]);
  }
#pragma unroll
  for (int r = 0; r < 4; ++r) {
    int m = m0 + ty * 4 + r;
#pragma unroll
    for (int c = 0; c < 4; ++c) {
      int e = n0 + tx * 4 + c;
      float val = acc[r][c] + bias[e];
      float sg = 1.f / (1.f + __expf(-val));
      attn2[(size_t)m * E + e] = context[(size_t)m * E + e] * sg;
    }
  }
}

// ---------------- grouped out projection + bias + transpose to [S,B,E] ---------
__global__ __launch_bounds__(256) void mha_out(const float* __restrict__ attn2,
                                               const float* __restrict__ w,
                                               const float* __restrict__ bias,
                                               float* __restrict__ outp) {
  __shared__ float As[64][97];
  __shared__ float Ws[96][97];
  const int m0 = blockIdx.x * 64;
  const int g = blockIdx.y;
  const int n0 = g * 96;
  const int tid = threadIdx.x;
  for (int idx = tid; idx < 64 * 96; idx += 256) {
    int m = idx / 96, j = idx - m * 96;
    As[m][j] = attn2[(size_t)(m0 + m) * E + g * 96 + j];
  }
  for (int idx = tid; idx < 96 * 96; idx += 256) {
    int n = idx / 96, j = idx - n * 96;
    Ws[n][j] = w[(size_t)(n0 + n) * 96 + j];
  }
  __syncthreads();
  const int tx = tid & 15, ty = tid >> 4;
  float acc[4][6] = {};
  for (int j = 0; j < 96; ++j) {
    float a[4], bb[6];
#pragma unroll
    for (int r = 0; r < 4; ++r) a[r] = As[ty * 4 + r][j];
#pragma unroll
    for (int c = 0; c < 6; ++c) bb[c] = Ws[tx * 6 + c][j];
#pragma unroll
    for (int r = 0; r < 4; ++r)
#pragma unroll
      for (int c = 0; c < 6; ++c) acc[r][c] = fmaf(a[r], bb[c], acc[r][c]);
  }
#pragma unroll
  for (int r = 0; r < 4; ++r) {
    int m = m0 + ty * 4 + r;
    int b = m / S, s = m - b * S;  // rows here are r = b*S + s
#pragma unroll
    for (int c = 0; c < 6; ++c) {
      int p = n0 + tx * 6 + c;
      outp[((size_t)s * B + b) * E + p] = acc[r][c] + bias[p];
    }
  }
}

// ---------------- host launcher ------------------------------------------------
extern "C" void kernel_launch(void* const* d_in, const int* in_sizes, int n_in,
                              void* d_out, int out_size, void* d_ws, size_t ws_size,
                              hipStream_t stream) {
  const float* query = (const float*)d_in[0];
  const float* qkv_w = (const float*)d_in[3];
  const float* qkv_b = (const float*)d_in[4];
  const float* out_w = (const float*)d_in[5];
  const float* out_b = (const float*)d_in[6];
  const float* rel   = (const float*)d_in[7];
  const float* ln_g  = (const float*)d_in[8];
  const float* ln_b  = (const float*)d_in[9];
  const float* fc1_w = (const float*)d_in[10];
  const float* fc1_b = (const float*)d_in[11];
  const float* fc2_w = (const float*)d_in[12];
  const float* fc2_b = (const float*)d_in[13];

  float* ws = (float*)d_ws;
  float* qhat    = ws;                 // [B,H,S,D]
  float* khat    = ws + SBE;           // [B,H,S,D]
  float* vbuf    = ws + 2 * SBE;       // [B,H,S,D]
  float* ybuf    = ws + 3 * SBE;       // y chunk (<=3200*2304 fl) / later context
  float* context = ws + 3 * SBE;       // rows b*S+s, [.,768] (aliases ybuf)
  float* Rbuf    = ws + 4 * SBE;       // 197*197
  float* lnbuf = qhat;   // reuse after attention
  float* h1    = khat;   // reuse
  float* attn2 = vbuf;   // reuse
  float* outp  = (float*)d_out;
  float* avgp  = outp + SBE;

  hipMemsetAsync(avgp, 0, AVGN * sizeof(float), stream);
  mha_relR<<<(S * S + 255) / 256, 256, 0, stream>>>(rel, Rbuf);

  // qkv two-pass, chunked over m (ybuf <= SBE floats)
  const int CH = 3200;  // multiple of 64 and 32
  for (int mbase = 0; mbase < M; mbase += CH) {
    int rows = (M - mbase < CH) ? (M - mbase) : CH;
    mha_qkv_gemm<<<dim3(rows / 64, 24), 256, 0, stream>>>(query, qkv_w, qkv_b, ybuf,
                                                          mbase, rows);
    mha_qkv_shuffle<<<dim3(rows / 32, 36), 256, 0, stream>>>(ybuf, rel, qhat, khat,
                                                             vbuf, mbase, rows);
  }

  mha_fattn<<<dim3(B * H, (S + 31) / 32), 256, 0, stream>>>(qhat, khat, vbuf, Rbuf,
                                                            context, avgp);

  mha_ln<<<M, 256, 0, stream>>>(context, ln_g, ln_b, lnbuf);
  mha_fc1<<<M / 64, 256, 0, stream>>>(lnbuf, fc1_w, fc1_b, h1);
  mha_fc2<<<dim3(M / 64, 12), 256, 0, stream>>>(h1, fc2_w, fc2_b, context, attn2);
  mha_out<<<dim3(M / 64, 8), 256, 0, stream>>>(attn2, out_w, out_b, outp);
}